// Round 1
// baseline (660.610 us; speedup 1.0000x reference)
//
#include <hip/hip_runtime.h>
#include <hip/hip_bf16.h>

// Problem constants (from reference)
#define NN 50000      // nodes
#define NE 800000     // edges
#define NS 2          // samples
#define DIN 128
#define DNOISE 64
#define DH0 192       // DIN + DNOISE
#define DOUT 256      // D0 == D1
#define NB 49         // scan blocks = ceil(NN/1024)

typedef __bf16 bf16x8 __attribute__((ext_vector_type(8)));
typedef float floatx4 __attribute__((ext_vector_type(4)));

// ---------------- bf16 helpers (uint = packed bf16 pair) ----------------

__device__ inline float bflo(unsigned int u) { return __uint_as_float(u << 16); }
__device__ inline float bfhi(unsigned int u) { return __uint_as_float(u & 0xffff0000u); }
__device__ inline unsigned short f2bf_bits(float x) {
    __hip_bfloat16 b = __float2bfloat16(x);
    return *reinterpret_cast<unsigned short*>(&b);
}
__device__ inline unsigned int pack2(float lo, float hi) {
    return (unsigned int)f2bf_bits(lo) | ((unsigned int)f2bf_bits(hi) << 16);
}

// ---------------- CSR build ----------------

__global__ void count_kernel(const int* __restrict__ dst, int* __restrict__ cnt) {
    int i = blockIdx.x * blockDim.x + threadIdx.x;
    if (i < NE) atomicAdd(&cnt[dst[i]], 1);
}

// Phase A: per-block reduce of counts -> bsum[49]
__global__ __launch_bounds__(1024) void scanA_kernel(const int* __restrict__ cnt, int* __restrict__ bsum) {
    int i = blockIdx.x * 1024 + threadIdx.x;
    int v = (i < NN) ? cnt[i] : 0;
    for (int off = 32; off > 0; off >>= 1) v += __shfl_down(v, off);
    __shared__ int wsum[16];
    if ((threadIdx.x & 63) == 0) wsum[threadIdx.x >> 6] = v;
    __syncthreads();
    if (threadIdx.x == 0) {
        int s = 0;
        for (int k = 0; k < 16; ++k) s += wsum[k];
        bsum[blockIdx.x] = s;
    }
}

// Phase B: exclusive scan of 49 block sums (single wave, shfl scan)
__global__ __launch_bounds__(64) void scanB_kernel(int* __restrict__ bsum) {
    int lane = threadIdx.x;
    int orig = (lane < NB) ? bsum[lane] : 0;
    int v = orig;
    for (int off = 1; off < 64; off <<= 1) {
        int t = __shfl_up(v, off);
        if (lane >= off) v += t;
    }
    if (lane < NB) bsum[lane] = v - orig;  // exclusive
}

// Phase C: intra-block scan + block offset -> row_ptr, cursor
__global__ __launch_bounds__(1024) void scanC_kernel(int* __restrict__ cnt, const int* __restrict__ bsum,
                                                     int* __restrict__ row_ptr) {
    __shared__ int buf[1024];
    int tid = threadIdx.x;
    int i = blockIdx.x * 1024 + tid;
    int v = (i < NN) ? cnt[i] : 0;
    buf[tid] = v;
    __syncthreads();
    for (int off = 1; off < 1024; off <<= 1) {
        int t = (tid >= off) ? buf[tid - off] : 0;
        __syncthreads();
        buf[tid] += t;
        __syncthreads();
    }
    int excl = buf[tid] - v + bsum[blockIdx.x];
    if (i < NN) { row_ptr[i + 1] = excl + v; cnt[i] = excl; }  // cnt becomes write cursor
    if (i == 0) row_ptr[0] = 0;
}

__global__ void fill_kernel(const int* __restrict__ src, const int* __restrict__ dst,
                            int* __restrict__ cursor, int* __restrict__ col_idx) {
    int i = blockIdx.x * blockDim.x + threadIdx.x;
    if (i < NE) {
        int p = atomicAdd(&cursor[dst[i]], 1);
        col_idx[p] = src[i];
    }
}

// ---------------- input prep: X fp32->bf16 + noise fp32 -> bitpacked uint2 ----------------
// blocks [0, XB4): X convert (float4 granularity). blocks [XB4, XB4+NR): noise rows.
// Noise branch ALSO writes the epsilon passthrough output (fuses old copy_eps).
#define XQ (NN * DIN / 4)          // 1.6M float4 units
#define XB4 ((XQ + 255) / 256)     // 6250
#define NR_BLOCKS ((NS * NN + 255) / 256)  // 391

__global__ void prep_kernel(const float* __restrict__ X, unsigned short* __restrict__ Xb,
                            const float* __restrict__ noise, uint2* __restrict__ Nbit,
                            float* __restrict__ out_eps) {
    int b = blockIdx.x;
    if (b < XB4) {
        int i = b * 256 + threadIdx.x;
        if (i < XQ) {
            float4 v = reinterpret_cast<const float4*>(X)[i];
            ushort4 o;
            o.x = f2bf_bits(v.x); o.y = f2bf_bits(v.y); o.z = f2bf_bits(v.z); o.w = f2bf_bits(v.w);
            reinterpret_cast<ushort4*>(Xb)[i] = o;
        }
    } else {
        int r = (b - XB4) * 256 + threadIdx.x;  // (s*NN + node)
        if (r < NS * NN) {
            const float4* p = reinterpret_cast<const float4*>(noise + (size_t)r * DNOISE);
            float4* oe = reinterpret_cast<float4*>(out_eps + (size_t)r * DNOISE);
            unsigned int lo = 0, hi = 0;
            for (int q = 0; q < 8; ++q) {
                float4 v = p[q];
                oe[q] = v;
                int base = q * 4;
                lo |= (v.x != 0.f ? 1u : 0u) << base;
                lo |= (v.y != 0.f ? 1u : 0u) << (base + 1);
                lo |= (v.z != 0.f ? 1u : 0u) << (base + 2);
                lo |= (v.w != 0.f ? 1u : 0u) << (base + 3);
            }
            for (int q = 8; q < 16; ++q) {
                float4 v = p[q];
                oe[q] = v;
                int base = q * 4 - 32;
                hi |= (v.x != 0.f ? 1u : 0u) << base;
                hi |= (v.y != 0.f ? 1u : 0u) << (base + 1);
                hi |= (v.z != 0.f ? 1u : 0u) << (base + 2);
                hi |= (v.w != 0.f ? 1u : 0u) << (base + 3);
            }
            uint2 o; o.x = lo; o.y = hi;
            Nbit[r] = o;
        }
    }
}

// ---------------- W transposes, both layers in one launch ----------------

__global__ void transpose_both(const float* __restrict__ W0, const float* __restrict__ W1,
                               __hip_bfloat16* __restrict__ Wt0, __hip_bfloat16* __restrict__ Wt1) {
    int b = blockIdx.x;
    if (b < DOUT) {
        for (int k = threadIdx.x; k < DH0; k += blockDim.x)
            Wt0[(size_t)b * DH0 + k] = __float2bfloat16(W0[(size_t)k * DOUT + b]);
    } else {
        int n = b - DOUT;
        for (int k = threadIdx.x; k < DOUT; k += blockDim.x)
            Wt1[(size_t)n * DOUT + k] = __float2bfloat16(W1[(size_t)k * DOUT + n]);
    }
}

// ---------------- Layer 0 aggregation ----------------
// 2 nodes/block (slot = tid>>7), 128 threads/node:
//   cc in [0,64): X uints, gathered from Xb, written to BOTH samples (dedup).
//   cc in [64,128): noise via bitpacked table (L2-resident, 800 KB): j=cc-64,
//     s=j>>5, c=j&31 -> dims 2c,2c+1; per edge one broadcast 8B load + bit extract,
//     integer accumulate (exact).

__global__ __launch_bounds__(256) void agg0_kernel(
    const unsigned int* __restrict__ Xb,   // [NN][64] packed bf16 pairs
    const uint2* __restrict__ Nbit,        // [NS*NN] 64 noise bits
    const int* __restrict__ row_ptr, const int* __restrict__ col_idx,
    const float* __restrict__ eps0p,
    unsigned int* __restrict__ z0) {       // [NS*NN][96]
    const int d = blockIdx.x * 2 + (threadIdx.x >> 7);
    const int cc = threadIdx.x & 127;
    const float c = 1.f + eps0p[0];
    const int beg = row_ptr[d], end = row_ptr[d + 1];
    if (cc < 64) {
        const unsigned int* src = Xb + cc;
        unsigned int u = src[(size_t)d * 64];
        float aL = c * bflo(u), aH = c * bfhi(u);
        int e = beg;
        for (; e + 3 < end; e += 4) {
            int i0 = col_idx[e], i1 = col_idx[e + 1], i2 = col_idx[e + 2], i3 = col_idx[e + 3];
            unsigned int u0 = src[(size_t)i0 * 64], u1 = src[(size_t)i1 * 64];
            unsigned int u2 = src[(size_t)i2 * 64], u3 = src[(size_t)i3 * 64];
            aL += (bflo(u0) + bflo(u1)) + (bflo(u2) + bflo(u3));
            aH += (bfhi(u0) + bfhi(u1)) + (bfhi(u2) + bfhi(u3));
        }
        for (; e < end; ++e) {
            unsigned int ue = src[(size_t)col_idx[e] * 64];
            aL += bflo(ue); aH += bfhi(ue);
        }
        unsigned int r = pack2(aL, aH);
        z0[(size_t)d * 96 + cc] = r;             // sample 0
        z0[(size_t)(NN + d) * 96 + cc] = r;      // sample 1 (X part sample-independent)
    } else {
        int j = cc - 64;
        int s = j >> 5, col = j & 31;            // dims 2*col, 2*col+1
        const uint2* src = Nbit + (size_t)s * NN;
        const int word = col >> 4;               // 0 -> .x, 1 -> .y
        const int sh = (2 * col) & 31;
        uint2 uS = src[d];
        unsigned int wS = word ? uS.y : uS.x;
        int c0 = 0, c1 = 0;
        int e = beg;
        for (; e + 3 < end; e += 4) {
            uint2 u0 = src[col_idx[e]], u1 = src[col_idx[e + 1]];
            uint2 u2 = src[col_idx[e + 2]], u3 = src[col_idx[e + 3]];
            unsigned int w0 = word ? u0.y : u0.x, w1 = word ? u1.y : u1.x;
            unsigned int w2 = word ? u2.y : u2.x, w3 = word ? u3.y : u3.x;
            c0 += (int)((w0 >> sh) & 1) + (int)((w1 >> sh) & 1) + (int)((w2 >> sh) & 1) + (int)((w3 >> sh) & 1);
            c1 += (int)((w0 >> (sh + 1)) & 1) + (int)((w1 >> (sh + 1)) & 1) +
                  (int)((w2 >> (sh + 1)) & 1) + (int)((w3 >> (sh + 1)) & 1);
        }
        for (; e < end; ++e) {
            uint2 ue = src[col_idx[e]];
            unsigned int we = word ? ue.y : ue.x;
            c0 += (int)((we >> sh) & 1);
            c1 += (int)((we >> (sh + 1)) & 1);
        }
        float aL = c * (float)((wS >> sh) & 1) + (float)c0;
        float aH = c * (float)((wS >> (sh + 1)) & 1) + (float)c1;
        z0[(size_t)(s * NN + d) * 96 + 64 + col] = pack2(aL, aH);
    }
}

// ---------------- Layer 1 aggregation ----------------
// h1 is sample-INTERLEAVED: [node][s][256] bf16 = 1 KB/node = 64 uint4.
// One wave per node: 64 lanes x uint4 = full 1 KB (both samples) fetched in a
// SINGLE global_load_dwordx4 per edge. readfirstlane scalarizes the CSR walk
// (col_idx via s_load). x8 unroll keeps 8 KB/wave of gathers in flight.
// Accumulation order per dim identical to previous version (bit-identical out).

__global__ __launch_bounds__(256) void agg1_kernel(
    const uint4* __restrict__ h,           // [NN][64] uint4, sample-interleaved
    const int* __restrict__ row_ptr, const int* __restrict__ col_idx,
    const float* __restrict__ eps1p,
    uint4* __restrict__ z1) {              // [NS*NN][32] uint4 (standard layout)
    const int d = blockIdx.x * 4 + (threadIdx.x >> 6);
    const int lane = threadIdx.x & 63;
    const float c = 1.f + eps1p[0];
    const int beg = __builtin_amdgcn_readfirstlane(row_ptr[d]);
    const int end = __builtin_amdgcn_readfirstlane(row_ptr[d + 1]);
    const uint4* src = h + lane;
    uint4 u = src[(size_t)d * 64];
    float a0 = c * bflo(u.x), a1 = c * bfhi(u.x);
    float a2 = c * bflo(u.y), a3 = c * bfhi(u.y);
    float a4 = c * bflo(u.z), a5 = c * bfhi(u.z);
    float a6 = c * bflo(u.w), a7 = c * bfhi(u.w);
    int e = beg;
    for (; e + 7 < end; e += 8) {
        uint4 g[8];
#pragma unroll
        for (int q = 0; q < 8; ++q) g[q] = src[(size_t)col_idx[e + q] * 64];
#pragma unroll
        for (int q = 0; q < 8; ++q) {
            a0 += bflo(g[q].x); a1 += bfhi(g[q].x);
            a2 += bflo(g[q].y); a3 += bfhi(g[q].y);
            a4 += bflo(g[q].z); a5 += bfhi(g[q].z);
            a6 += bflo(g[q].w); a7 += bfhi(g[q].w);
        }
    }
    if (e + 3 < end) {
        uint4 g[4];
#pragma unroll
        for (int q = 0; q < 4; ++q) g[q] = src[(size_t)col_idx[e + q] * 64];
#pragma unroll
        for (int q = 0; q < 4; ++q) {
            a0 += bflo(g[q].x); a1 += bfhi(g[q].x);
            a2 += bflo(g[q].y); a3 += bfhi(g[q].y);
            a4 += bflo(g[q].z); a5 += bfhi(g[q].z);
            a6 += bflo(g[q].w); a7 += bfhi(g[q].w);
        }
        e += 4;
    }
    for (; e < end; ++e) {
        uint4 ge = src[(size_t)col_idx[e] * 64];
        a0 += bflo(ge.x); a1 += bfhi(ge.x);
        a2 += bflo(ge.y); a3 += bfhi(ge.y);
        a4 += bflo(ge.z); a5 += bfhi(ge.z);
        a6 += bflo(ge.w); a7 += bfhi(ge.w);
    }
    const int s = lane >> 5, q = lane & 31;
    uint4 r;
    r.x = pack2(a0, a1); r.y = pack2(a2, a3);
    r.z = pack2(a4, a5); r.w = pack2(a6, a7);
    z1[(size_t)(s * NN + d) * 32 + q] = r;
}

// ---------------- GEMM: C = relu(A @ W + b), N fixed at 256 ----------------
// Each wave: 32 rows (two 16-row tiles sharing each B fragment) x 256 cols.
// Layouts (m89/m120-verified): A[m=lane&15][k=quad*8+j]; B[k=quad*8+j][n=lane&15];
// D: col=lane&15, row=quad*4+reg.
// SWZ=true: output row m = s*NN+node is stored at row node*2+s (sample-interleaved).

__device__ inline void store_out(float* C, size_t idx, float v) { C[idx] = v; }
__device__ inline void store_out(__hip_bfloat16* C, size_t idx, float v) { C[idx] = __float2bfloat16(v); }

template <bool SWZ, typename OUT_T>
__global__ __launch_bounds__(256) void gemm_bias_relu(
    const __hip_bfloat16* __restrict__ A, const __hip_bfloat16* __restrict__ Wt,
    const float* __restrict__ bias, OUT_T* __restrict__ C,
    int M, int K) {
    const int lane = threadIdx.x & 63;
    const int wave = threadIdx.x >> 6;
    const int rowBase = blockIdx.x * 128 + wave * 32;   // M % 32 == 0
    if (rowBase >= M) return;
    const int lo = lane & 15;
    const int quad = lane >> 4;

    floatx4 acc0[16], acc1[16];
#pragma unroll
    for (int t = 0; t < 16; ++t) {
        acc0[t] = (floatx4){0.f, 0.f, 0.f, 0.f};
        acc1[t] = (floatx4){0.f, 0.f, 0.f, 0.f};
    }

    const __hip_bfloat16* arow0 = A + (size_t)(rowBase + lo) * K + quad * 8;
    const __hip_bfloat16* arow1 = arow0 + (size_t)16 * K;
    for (int k0 = 0; k0 < K; k0 += 32) {
        bf16x8 a0 = *reinterpret_cast<const bf16x8*>(arow0 + k0);
        bf16x8 a1 = *reinterpret_cast<const bf16x8*>(arow1 + k0);
#pragma unroll
        for (int t = 0; t < 16; ++t) {
            bf16x8 b = *reinterpret_cast<const bf16x8*>(Wt + (size_t)(t * 16 + lo) * K + k0 + quad * 8);
            acc0[t] = __builtin_amdgcn_mfma_f32_16x16x32_bf16(a0, b, acc0[t], 0, 0, 0);
            acc1[t] = __builtin_amdgcn_mfma_f32_16x16x32_bf16(a1, b, acc1[t], 0, 0, 0);
        }
    }

#pragma unroll
    for (int t = 0; t < 16; ++t) {
        int col = t * 16 + lo;
        float bv = bias[col];
#pragma unroll
        for (int r = 0; r < 4; ++r) {
            int m0 = rowBase + quad * 4 + r;
            int m1 = m0 + 16;
            size_t o0 = SWZ ? ((m0 < NN) ? (size_t)m0 * 2 : (size_t)(m0 - NN) * 2 + 1) : (size_t)m0;
            size_t o1 = SWZ ? ((m1 < NN) ? (size_t)m1 * 2 : (size_t)(m1 - NN) * 2 + 1) : (size_t)m1;
            float v0 = acc0[t][r] + bv;
            store_out(C, o0 * DOUT + col, v0 > 0.f ? v0 : 0.f);
            float v1 = acc1[t][r] + bv;
            store_out(C, o1 * DOUT + col, v1 > 0.f ? v1 : 0.f);
        }
    }
}

extern "C" void kernel_launch(void* const* d_in, const int* in_sizes, int n_in,
                              void* d_out, int out_size, void* d_ws, size_t ws_size,
                              hipStream_t stream) {
    const float* X = (const float*)d_in[0];
    const float* noise = (const float*)d_in[1];
    const int* esrc = (const int*)d_in[2];
    const int* edst = (const int*)d_in[3];
    const float* W0 = (const float*)d_in[4];
    const float* b0 = (const float*)d_in[5];
    const float* W1 = (const float*)d_in[6];
    const float* b1 = (const float*)d_in[7];
    const float* eps0 = (const float*)d_in[8];
    const float* eps1 = (const float*)d_in[9];
    float* out = (float*)d_out;

    const int M = NS * NN;  // 100000

    // Workspace carve (~56 MB, proven footprint).
    char* w = (char*)d_ws;
    auto carve = [&](size_t bytes) { char* p = w; w += (bytes + 511) & ~(size_t)511; return p; };
    int* cursor = (int*)carve((size_t)NN * 4);
    int* row_ptr = (int*)carve((size_t)(NN + 1) * 4);
    int* col_idx = (int*)carve((size_t)NE * 4);
    int* bsum = (int*)carve((size_t)NB * 4);
    uint2* Nbit = (uint2*)carve((size_t)M * 8);                    // 800 KB, L2-resident
    __hip_bfloat16* Wt0 = (__hip_bfloat16*)carve((size_t)DH0 * DOUT * 2);
    __hip_bfloat16* Wt1 = (__hip_bfloat16*)carve((size_t)DOUT * DOUT * 2);
    unsigned int* z = (unsigned int*)carve((size_t)M * DOUT * 2);  // z0 (96 uints/row) then z1 (32 uint4/row)

    // h1 (bf16, sample-interleaved [node][2][256], 51.2 MB) staged at the start
    // of the fp32 out region (102.4 MB); dead before gemm1 overwrites it.
    __hip_bfloat16* h1 = (__hip_bfloat16*)d_out;
    // bf16 X copy (12.8 MB) lives in the TAIL of the z region: z0 occupies
    // [M][96] uints = 38.4 MB of the 51.2 MB carve; the remaining 12.8 MB
    // exactly fits Xb. Xb is dead after agg0; agg1's z1 write overwrites it.
    // This frees the epsilon output region so prep writes epsilon directly.
    unsigned short* Xb = (unsigned short*)(z + (size_t)M * 96);

    hipMemsetAsync(cursor, 0, (size_t)NN * 4, stream);
    count_kernel<<<(NE + 255) / 256, 256, 0, stream>>>(edst, cursor);
    scanA_kernel<<<NB, 1024, 0, stream>>>(cursor, bsum);
    scanB_kernel<<<1, 64, 0, stream>>>(bsum);
    scanC_kernel<<<NB, 1024, 0, stream>>>(cursor, bsum, row_ptr);
    fill_kernel<<<(NE + 255) / 256, 256, 0, stream>>>(esrc, edst, cursor, col_idx);
    prep_kernel<<<XB4 + NR_BLOCKS, 256, 0, stream>>>(X, Xb, noise, Nbit,
                                                     out + (size_t)M * DOUT);
    transpose_both<<<2 * DOUT, 256, 0, stream>>>(W0, W1, Wt0, Wt1);

    agg0_kernel<<<NN / 2, 256, 0, stream>>>(
        (const unsigned int*)Xb, Nbit, row_ptr, col_idx, eps0, z);
    gemm_bias_relu<true, __hip_bfloat16><<<(M + 127) / 128, 256, 0, stream>>>(
        (const __hip_bfloat16*)z, Wt0, b0, h1, M, DH0);
    agg1_kernel<<<NN / 4, 256, 0, stream>>>(
        (const uint4*)h1, row_ptr, col_idx, eps1, (uint4*)z);
    gemm_bias_relu<false, float><<<(M + 127) / 128, 256, 0, stream>>>(
        (const __hip_bfloat16*)z, Wt1, b1, out, M, DOUT);
}

// Round 2
// 633.724 us; speedup vs baseline: 1.0424x; 1.0424x over previous
//
#include <hip/hip_runtime.h>
#include <hip/hip_bf16.h>

// Problem constants (from reference)
#define NN 50000      // nodes
#define NE 800000     // edges
#define NS 2          // samples
#define DIN 128
#define DNOISE 64
#define DH0 192       // DIN + DNOISE
#define DOUT 256      // D0 == D1
#define NB 49         // scan blocks = ceil(NN/1024)

typedef __bf16 bf16x8 __attribute__((ext_vector_type(8)));
typedef float floatx4 __attribute__((ext_vector_type(4)));

// ---------------- bf16 helpers (uint = packed bf16 pair) ----------------

__device__ inline float bflo(unsigned int u) { return __uint_as_float(u << 16); }
__device__ inline float bfhi(unsigned int u) { return __uint_as_float(u & 0xffff0000u); }
__device__ inline unsigned short f2bf_bits(float x) {
    __hip_bfloat16 b = __float2bfloat16(x);
    return *reinterpret_cast<unsigned short*>(&b);
}
__device__ inline unsigned int pack2(float lo, float hi) {
    return (unsigned int)f2bf_bits(lo) | ((unsigned int)f2bf_bits(hi) << 16);
}

// ---------------- CSR build ----------------

__global__ void count_kernel(const int* __restrict__ dst, int* __restrict__ cnt) {
    int i = blockIdx.x * blockDim.x + threadIdx.x;
    if (i < NE) atomicAdd(&cnt[dst[i]], 1);
}

// Phase A: per-block reduce of counts -> bsum[49]
__global__ __launch_bounds__(1024) void scanA_kernel(const int* __restrict__ cnt, int* __restrict__ bsum) {
    int i = blockIdx.x * 1024 + threadIdx.x;
    int v = (i < NN) ? cnt[i] : 0;
    for (int off = 32; off > 0; off >>= 1) v += __shfl_down(v, off);
    __shared__ int wsum[16];
    if ((threadIdx.x & 63) == 0) wsum[threadIdx.x >> 6] = v;
    __syncthreads();
    if (threadIdx.x == 0) {
        int s = 0;
        for (int k = 0; k < 16; ++k) s += wsum[k];
        bsum[blockIdx.x] = s;
    }
}

// Phase B: exclusive scan of 49 block sums (single wave, shfl scan)
__global__ __launch_bounds__(64) void scanB_kernel(int* __restrict__ bsum) {
    int lane = threadIdx.x;
    int orig = (lane < NB) ? bsum[lane] : 0;
    int v = orig;
    for (int off = 1; off < 64; off <<= 1) {
        int t = __shfl_up(v, off);
        if (lane >= off) v += t;
    }
    if (lane < NB) bsum[lane] = v - orig;  // exclusive
}

// Phase C: intra-block scan + block offset -> row_ptr, cursor
__global__ __launch_bounds__(1024) void scanC_kernel(int* __restrict__ cnt, const int* __restrict__ bsum,
                                                     int* __restrict__ row_ptr) {
    __shared__ int buf[1024];
    int tid = threadIdx.x;
    int i = blockIdx.x * 1024 + tid;
    int v = (i < NN) ? cnt[i] : 0;
    buf[tid] = v;
    __syncthreads();
    for (int off = 1; off < 1024; off <<= 1) {
        int t = (tid >= off) ? buf[tid - off] : 0;
        __syncthreads();
        buf[tid] += t;
        __syncthreads();
    }
    int excl = buf[tid] - v + bsum[blockIdx.x];
    if (i < NN) { row_ptr[i + 1] = excl + v; cnt[i] = excl; }  // cnt becomes write cursor
    if (i == 0) row_ptr[0] = 0;
}

__global__ void fill_kernel(const int* __restrict__ src, const int* __restrict__ dst,
                            int* __restrict__ cursor, int* __restrict__ col_idx) {
    int i = blockIdx.x * blockDim.x + threadIdx.x;
    if (i < NE) {
        int p = atomicAdd(&cursor[dst[i]], 1);
        col_idx[p] = src[i];
    }
}

// ---------------- input prep: X fp32->bf16 + noise fp32 -> bitpacked uint2 ----------------
// blocks [0, XB4): X convert (float4 granularity). blocks [XB4, XB4+NR): noise rows.
// Noise branch ALSO writes the epsilon passthrough output (fuses old copy_eps).
#define XQ (NN * DIN / 4)          // 1.6M float4 units
#define XB4 ((XQ + 255) / 256)     // 6250
#define NR_BLOCKS ((NS * NN + 255) / 256)  // 391

__global__ void prep_kernel(const float* __restrict__ X, unsigned short* __restrict__ Xb,
                            const float* __restrict__ noise, uint2* __restrict__ Nbit,
                            float* __restrict__ out_eps) {
    int b = blockIdx.x;
    if (b < XB4) {
        int i = b * 256 + threadIdx.x;
        if (i < XQ) {
            float4 v = reinterpret_cast<const float4*>(X)[i];
            ushort4 o;
            o.x = f2bf_bits(v.x); o.y = f2bf_bits(v.y); o.z = f2bf_bits(v.z); o.w = f2bf_bits(v.w);
            reinterpret_cast<ushort4*>(Xb)[i] = o;
        }
    } else {
        int r = (b - XB4) * 256 + threadIdx.x;  // (s*NN + node)
        if (r < NS * NN) {
            const float4* p = reinterpret_cast<const float4*>(noise + (size_t)r * DNOISE);
            float4* oe = reinterpret_cast<float4*>(out_eps + (size_t)r * DNOISE);
            unsigned int lo = 0, hi = 0;
            for (int q = 0; q < 8; ++q) {
                float4 v = p[q];
                oe[q] = v;
                int base = q * 4;
                lo |= (v.x != 0.f ? 1u : 0u) << base;
                lo |= (v.y != 0.f ? 1u : 0u) << (base + 1);
                lo |= (v.z != 0.f ? 1u : 0u) << (base + 2);
                lo |= (v.w != 0.f ? 1u : 0u) << (base + 3);
            }
            for (int q = 8; q < 16; ++q) {
                float4 v = p[q];
                oe[q] = v;
                int base = q * 4 - 32;
                hi |= (v.x != 0.f ? 1u : 0u) << base;
                hi |= (v.y != 0.f ? 1u : 0u) << (base + 1);
                hi |= (v.z != 0.f ? 1u : 0u) << (base + 2);
                hi |= (v.w != 0.f ? 1u : 0u) << (base + 3);
            }
            uint2 o; o.x = lo; o.y = hi;
            Nbit[r] = o;
        }
    }
}

// ---------------- W transposes, both layers in one launch ----------------

__global__ void transpose_both(const float* __restrict__ W0, const float* __restrict__ W1,
                               __hip_bfloat16* __restrict__ Wt0, __hip_bfloat16* __restrict__ Wt1) {
    int b = blockIdx.x;
    if (b < DOUT) {
        for (int k = threadIdx.x; k < DH0; k += blockDim.x)
            Wt0[(size_t)b * DH0 + k] = __float2bfloat16(W0[(size_t)k * DOUT + b]);
    } else {
        int n = b - DOUT;
        for (int k = threadIdx.x; k < DOUT; k += blockDim.x)
            Wt1[(size_t)n * DOUT + k] = __float2bfloat16(W1[(size_t)k * DOUT + n]);
    }
}

// ---------------- Layer 0 aggregation ----------------
// 2 nodes/block (slot = tid>>7), 128 threads/node:
//   cc in [0,64): X uints, gathered from Xb, written to BOTH samples (dedup).
//   cc in [64,128): noise via bitpacked table (L2-resident, 800 KB): j=cc-64,
//     s=j>>5, c=j&31 -> dims 2c,2c+1; per edge one broadcast 8B load + bit extract,
//     integer accumulate (exact).

__global__ __launch_bounds__(256) void agg0_kernel(
    const unsigned int* __restrict__ Xb,   // [NN][64] packed bf16 pairs
    const uint2* __restrict__ Nbit,        // [NS*NN] 64 noise bits
    const int* __restrict__ row_ptr, const int* __restrict__ col_idx,
    const float* __restrict__ eps0p,
    unsigned int* __restrict__ z0) {       // [NS*NN][96]
    const int d = blockIdx.x * 2 + (threadIdx.x >> 7);
    const int cc = threadIdx.x & 127;
    const float c = 1.f + eps0p[0];
    const int beg = row_ptr[d], end = row_ptr[d + 1];
    if (cc < 64) {
        const unsigned int* src = Xb + cc;
        unsigned int u = src[(size_t)d * 64];
        float aL = c * bflo(u), aH = c * bfhi(u);
        int e = beg;
        for (; e + 3 < end; e += 4) {
            int i0 = col_idx[e], i1 = col_idx[e + 1], i2 = col_idx[e + 2], i3 = col_idx[e + 3];
            unsigned int u0 = src[(size_t)i0 * 64], u1 = src[(size_t)i1 * 64];
            unsigned int u2 = src[(size_t)i2 * 64], u3 = src[(size_t)i3 * 64];
            aL += (bflo(u0) + bflo(u1)) + (bflo(u2) + bflo(u3));
            aH += (bfhi(u0) + bfhi(u1)) + (bfhi(u2) + bfhi(u3));
        }
        for (; e < end; ++e) {
            unsigned int ue = src[(size_t)col_idx[e] * 64];
            aL += bflo(ue); aH += bfhi(ue);
        }
        unsigned int r = pack2(aL, aH);
        z0[(size_t)d * 96 + cc] = r;             // sample 0
        z0[(size_t)(NN + d) * 96 + cc] = r;      // sample 1 (X part sample-independent)
    } else {
        int j = cc - 64;
        int s = j >> 5, col = j & 31;            // dims 2*col, 2*col+1
        const uint2* src = Nbit + (size_t)s * NN;
        const int word = col >> 4;               // 0 -> .x, 1 -> .y
        const int sh = (2 * col) & 31;
        uint2 uS = src[d];
        unsigned int wS = word ? uS.y : uS.x;
        int c0 = 0, c1 = 0;
        int e = beg;
        for (; e + 3 < end; e += 4) {
            uint2 u0 = src[col_idx[e]], u1 = src[col_idx[e + 1]];
            uint2 u2 = src[col_idx[e + 2]], u3 = src[col_idx[e + 3]];
            unsigned int w0 = word ? u0.y : u0.x, w1 = word ? u1.y : u1.x;
            unsigned int w2 = word ? u2.y : u2.x, w3 = word ? u3.y : u3.x;
            c0 += (int)((w0 >> sh) & 1) + (int)((w1 >> sh) & 1) + (int)((w2 >> sh) & 1) + (int)((w3 >> sh) & 1);
            c1 += (int)((w0 >> (sh + 1)) & 1) + (int)((w1 >> (sh + 1)) & 1) +
                  (int)((w2 >> (sh + 1)) & 1) + (int)((w3 >> (sh + 1)) & 1);
        }
        for (; e < end; ++e) {
            uint2 ue = src[col_idx[e]];
            unsigned int we = word ? ue.y : ue.x;
            c0 += (int)((we >> sh) & 1);
            c1 += (int)((we >> (sh + 1)) & 1);
        }
        float aL = c * (float)((wS >> sh) & 1) + (float)c0;
        float aH = c * (float)((wS >> (sh + 1)) & 1) + (float)c1;
        z0[(size_t)(s * NN + d) * 96 + 64 + col] = pack2(aL, aH);
    }
}

// ---------------- Layer 1 aggregation (per-sample launch) ----------------
// Round-0 proven structure (uint2 gathers, 512B/instr, x8 unroll), but split
// into two launches, one per sample: live gather footprint halves
// (51.2 MB -> 25.6 MB) to raise L2 temporal hit rate. Per-(node,s,col)
// accumulation order identical to round-0 (numerically identical output).
// Block = 128 threads = 2 waves = 2 nodes (one wave per node).

__global__ __launch_bounds__(128) void agg1_kernel(
    const uint2* __restrict__ h,           // [NS*NN][64] (uint2 = 4 bf16)
    const int* __restrict__ row_ptr, const int* __restrict__ col_idx,
    const float* __restrict__ eps1p,
    uint2* __restrict__ z1,                // [NS*NN][64]
    int s) {
    const int d = blockIdx.x * 2 + (threadIdx.x >> 6);
    const int cc = threadIdx.x & 63;
    const float c = 1.f + eps1p[0];
    const int beg = row_ptr[d], end = row_ptr[d + 1];
    const uint2* src = h + (size_t)s * NN * 64 + cc;
    uint2 u = src[(size_t)d * 64];
    float aL0 = c * bflo(u.x), aH0 = c * bfhi(u.x);
    float aL1 = c * bflo(u.y), aH1 = c * bfhi(u.y);
    int e = beg;
    for (; e + 7 < end; e += 8) {
        uint2 g[8];
#pragma unroll
        for (int q = 0; q < 8; ++q) g[q] = src[(size_t)col_idx[e + q] * 64];
#pragma unroll
        for (int q = 0; q < 8; ++q) {
            aL0 += bflo(g[q].x); aH0 += bfhi(g[q].x);
            aL1 += bflo(g[q].y); aH1 += bfhi(g[q].y);
        }
    }
    for (; e + 3 < end; e += 4) {
        uint2 u0 = src[(size_t)col_idx[e] * 64], u1 = src[(size_t)col_idx[e + 1] * 64];
        uint2 u2 = src[(size_t)col_idx[e + 2] * 64], u3 = src[(size_t)col_idx[e + 3] * 64];
        aL0 += (bflo(u0.x) + bflo(u1.x)) + (bflo(u2.x) + bflo(u3.x));
        aH0 += (bfhi(u0.x) + bfhi(u1.x)) + (bfhi(u2.x) + bfhi(u3.x));
        aL1 += (bflo(u0.y) + bflo(u1.y)) + (bflo(u2.y) + bflo(u3.y));
        aH1 += (bfhi(u0.y) + bfhi(u1.y)) + (bfhi(u2.y) + bfhi(u3.y));
    }
    for (; e < end; ++e) {
        uint2 ue = src[(size_t)col_idx[e] * 64];
        aL0 += bflo(ue.x); aH0 += bfhi(ue.x);
        aL1 += bflo(ue.y); aH1 += bfhi(ue.y);
    }
    uint2 r; r.x = pack2(aL0, aH0); r.y = pack2(aL1, aH1);
    z1[(size_t)(s * NN + d) * 64 + cc] = r;
}

// ---------------- GEMM: C = relu(A @ W + b), N fixed at 256 ----------------
// Each wave: 32 rows (two 16-row tiles sharing each B fragment) x 256 cols.
// Layouts (m89/m120-verified): A[m=lane&15][k=quad*8+j]; B[k=quad*8+j][n=lane&15];
// D: col=lane&15, row=quad*4+reg.

__device__ inline void store_out(float* C, size_t idx, float v) { C[idx] = v; }
__device__ inline void store_out(__hip_bfloat16* C, size_t idx, float v) { C[idx] = __float2bfloat16(v); }

template <typename OUT_T>
__global__ __launch_bounds__(256) void gemm_bias_relu(
    const __hip_bfloat16* __restrict__ A, const __hip_bfloat16* __restrict__ Wt,
    const float* __restrict__ bias, OUT_T* __restrict__ C,
    int M, int K) {
    const int lane = threadIdx.x & 63;
    const int wave = threadIdx.x >> 6;
    const int rowBase = blockIdx.x * 128 + wave * 32;   // M % 32 == 0
    if (rowBase >= M) return;
    const int lo = lane & 15;
    const int quad = lane >> 4;

    floatx4 acc0[16], acc1[16];
#pragma unroll
    for (int t = 0; t < 16; ++t) {
        acc0[t] = (floatx4){0.f, 0.f, 0.f, 0.f};
        acc1[t] = (floatx4){0.f, 0.f, 0.f, 0.f};
    }

    const __hip_bfloat16* arow0 = A + (size_t)(rowBase + lo) * K + quad * 8;
    const __hip_bfloat16* arow1 = arow0 + (size_t)16 * K;
    for (int k0 = 0; k0 < K; k0 += 32) {
        bf16x8 a0 = *reinterpret_cast<const bf16x8*>(arow0 + k0);
        bf16x8 a1 = *reinterpret_cast<const bf16x8*>(arow1 + k0);
#pragma unroll
        for (int t = 0; t < 16; ++t) {
            bf16x8 b = *reinterpret_cast<const bf16x8*>(Wt + (size_t)(t * 16 + lo) * K + k0 + quad * 8);
            acc0[t] = __builtin_amdgcn_mfma_f32_16x16x32_bf16(a0, b, acc0[t], 0, 0, 0);
            acc1[t] = __builtin_amdgcn_mfma_f32_16x16x32_bf16(a1, b, acc1[t], 0, 0, 0);
        }
    }

#pragma unroll
    for (int t = 0; t < 16; ++t) {
        int col = t * 16 + lo;
        float bv = bias[col];
#pragma unroll
        for (int r = 0; r < 4; ++r) {
            int row0 = rowBase + quad * 4 + r;
            float v0 = acc0[t][r] + bv;
            store_out(C, (size_t)row0 * DOUT + col, v0 > 0.f ? v0 : 0.f);
            float v1 = acc1[t][r] + bv;
            store_out(C, (size_t)(row0 + 16) * DOUT + col, v1 > 0.f ? v1 : 0.f);
        }
    }
}

extern "C" void kernel_launch(void* const* d_in, const int* in_sizes, int n_in,
                              void* d_out, int out_size, void* d_ws, size_t ws_size,
                              hipStream_t stream) {
    const float* X = (const float*)d_in[0];
    const float* noise = (const float*)d_in[1];
    const int* esrc = (const int*)d_in[2];
    const int* edst = (const int*)d_in[3];
    const float* W0 = (const float*)d_in[4];
    const float* b0 = (const float*)d_in[5];
    const float* W1 = (const float*)d_in[6];
    const float* b1 = (const float*)d_in[7];
    const float* eps0 = (const float*)d_in[8];
    const float* eps1 = (const float*)d_in[9];
    float* out = (float*)d_out;

    const int M = NS * NN;  // 100000

    // Workspace carve (~56 MB, proven footprint).
    char* w = (char*)d_ws;
    auto carve = [&](size_t bytes) { char* p = w; w += (bytes + 511) & ~(size_t)511; return p; };
    int* cursor = (int*)carve((size_t)NN * 4);
    int* row_ptr = (int*)carve((size_t)(NN + 1) * 4);
    int* col_idx = (int*)carve((size_t)NE * 4);
    int* bsum = (int*)carve((size_t)NB * 4);
    uint2* Nbit = (uint2*)carve((size_t)M * 8);                    // 800 KB, L2-resident
    __hip_bfloat16* Wt0 = (__hip_bfloat16*)carve((size_t)DH0 * DOUT * 2);
    __hip_bfloat16* Wt1 = (__hip_bfloat16*)carve((size_t)DOUT * DOUT * 2);
    unsigned int* z = (unsigned int*)carve((size_t)M * DOUT * 2);  // z0 (96 uints/row) then z1 (64 uint2/row)

    // h1 (bf16, [s][node][256], 51.2 MB) staged at the start of the fp32 out
    // region (102.4 MB); dead before gemm1 overwrites it.
    __hip_bfloat16* h1 = (__hip_bfloat16*)d_out;
    // bf16 X copy (12.8 MB) lives in the TAIL of the z region: z0 occupies
    // [M][96] uints = 38.4 MB of the 51.2 MB carve; the remaining 12.8 MB
    // exactly fits Xb. Xb is dead after agg0; agg1's z1 write overwrites it.
    // This frees the epsilon output region so prep writes epsilon directly.
    unsigned short* Xb = (unsigned short*)(z + (size_t)M * 96);

    hipMemsetAsync(cursor, 0, (size_t)NN * 4, stream);
    count_kernel<<<(NE + 255) / 256, 256, 0, stream>>>(edst, cursor);
    scanA_kernel<<<NB, 1024, 0, stream>>>(cursor, bsum);
    scanB_kernel<<<1, 64, 0, stream>>>(bsum);
    scanC_kernel<<<NB, 1024, 0, stream>>>(cursor, bsum, row_ptr);
    fill_kernel<<<(NE + 255) / 256, 256, 0, stream>>>(esrc, edst, cursor, col_idx);
    prep_kernel<<<XB4 + NR_BLOCKS, 256, 0, stream>>>(X, Xb, noise, Nbit,
                                                     out + (size_t)M * DOUT);
    transpose_both<<<2 * DOUT, 256, 0, stream>>>(W0, W1, Wt0, Wt1);

    agg0_kernel<<<NN / 2, 256, 0, stream>>>(
        (const unsigned int*)Xb, Nbit, row_ptr, col_idx, eps0, z);
    gemm_bias_relu<__hip_bfloat16><<<(M + 127) / 128, 256, 0, stream>>>(
        (const __hip_bfloat16*)z, Wt0, b0, h1, M, DH0);
    agg1_kernel<<<NN / 2, 128, 0, stream>>>(
        (const uint2*)h1, row_ptr, col_idx, eps1, (uint2*)z, 0);
    agg1_kernel<<<NN / 2, 128, 0, stream>>>(
        (const uint2*)h1, row_ptr, col_idx, eps1, (uint2*)z, 1);
    gemm_bias_relu<float><<<(M + 127) / 128, 256, 0, stream>>>(
        (const __hip_bfloat16*)z, Wt1, b1, out, M, DOUT);
}

// Round 3
// 614.497 us; speedup vs baseline: 1.0750x; 1.0313x over previous
//
#include <hip/hip_runtime.h>
#include <hip/hip_bf16.h>

// Problem constants (from reference)
#define NN 50000      // nodes
#define NE 800000     // edges
#define NS 2          // samples
#define DIN 128
#define DNOISE 64
#define DH0 192       // DIN + DNOISE
#define DOUT 256      // D0 == D1
#define NB 49         // scan blocks = ceil(NN/1024)

typedef __bf16 bf16x8 __attribute__((ext_vector_type(8)));
typedef float floatx4 __attribute__((ext_vector_type(4)));

// ---------------- bf16 helpers (uint = packed bf16 pair) ----------------

__device__ inline float bflo(unsigned int u) { return __uint_as_float(u << 16); }
__device__ inline float bfhi(unsigned int u) { return __uint_as_float(u & 0xffff0000u); }
__device__ inline unsigned short f2bf_bits(float x) {
    __hip_bfloat16 b = __float2bfloat16(x);
    return *reinterpret_cast<unsigned short*>(&b);
}
__device__ inline unsigned int pack2(float lo, float hi) {
    return (unsigned int)f2bf_bits(lo) | ((unsigned int)f2bf_bits(hi) << 16);
}

// ---------------- CSR build ----------------

__global__ void count_kernel(const int* __restrict__ dst, int* __restrict__ cnt) {
    int i = blockIdx.x * blockDim.x + threadIdx.x;
    if (i < NE) atomicAdd(&cnt[dst[i]], 1);
}

// Phase A: per-block reduce of counts -> bsum[49]
__global__ __launch_bounds__(1024) void scanA_kernel(const int* __restrict__ cnt, int* __restrict__ bsum) {
    int i = blockIdx.x * 1024 + threadIdx.x;
    int v = (i < NN) ? cnt[i] : 0;
    for (int off = 32; off > 0; off >>= 1) v += __shfl_down(v, off);
    __shared__ int wsum[16];
    if ((threadIdx.x & 63) == 0) wsum[threadIdx.x >> 6] = v;
    __syncthreads();
    if (threadIdx.x == 0) {
        int s = 0;
        for (int k = 0; k < 16; ++k) s += wsum[k];
        bsum[blockIdx.x] = s;
    }
}

// Phase B: exclusive scan of 49 block sums (single wave, shfl scan)
__global__ __launch_bounds__(64) void scanB_kernel(int* __restrict__ bsum) {
    int lane = threadIdx.x;
    int orig = (lane < NB) ? bsum[lane] : 0;
    int v = orig;
    for (int off = 1; off < 64; off <<= 1) {
        int t = __shfl_up(v, off);
        if (lane >= off) v += t;
    }
    if (lane < NB) bsum[lane] = v - orig;  // exclusive
}

// Phase C: intra-block scan + block offset -> row_ptr, cursor
__global__ __launch_bounds__(1024) void scanC_kernel(int* __restrict__ cnt, const int* __restrict__ bsum,
                                                     int* __restrict__ row_ptr) {
    __shared__ int buf[1024];
    int tid = threadIdx.x;
    int i = blockIdx.x * 1024 + tid;
    int v = (i < NN) ? cnt[i] : 0;
    buf[tid] = v;
    __syncthreads();
    for (int off = 1; off < 1024; off <<= 1) {
        int t = (tid >= off) ? buf[tid - off] : 0;
        __syncthreads();
        buf[tid] += t;
        __syncthreads();
    }
    int excl = buf[tid] - v + bsum[blockIdx.x];
    if (i < NN) { row_ptr[i + 1] = excl + v; cnt[i] = excl; }  // cnt becomes write cursor
    if (i == 0) row_ptr[0] = 0;
}

__global__ void fill_kernel(const int* __restrict__ src, const int* __restrict__ dst,
                            int* __restrict__ cursor, int* __restrict__ col_idx) {
    int i = blockIdx.x * blockDim.x + threadIdx.x;
    if (i < NE) {
        int p = atomicAdd(&cursor[dst[i]], 1);
        col_idx[p] = src[i];
    }
}

// ---------------- input prep: X fp32->bf16 + noise fp32 -> bitpacked uint2 ----------------
// blocks [0, XB4): X convert (float4 granularity). blocks [XB4, XB4+NR): noise rows.
// Noise branch ALSO writes the epsilon passthrough output (fuses old copy_eps).
#define XQ (NN * DIN / 4)          // 1.6M float4 units
#define XB4 ((XQ + 255) / 256)     // 6250
#define NR_BLOCKS ((NS * NN + 255) / 256)  // 391

__global__ void prep_kernel(const float* __restrict__ X, unsigned short* __restrict__ Xb,
                            const float* __restrict__ noise, uint2* __restrict__ Nbit,
                            float* __restrict__ out_eps) {
    int b = blockIdx.x;
    if (b < XB4) {
        int i = b * 256 + threadIdx.x;
        if (i < XQ) {
            float4 v = reinterpret_cast<const float4*>(X)[i];
            ushort4 o;
            o.x = f2bf_bits(v.x); o.y = f2bf_bits(v.y); o.z = f2bf_bits(v.z); o.w = f2bf_bits(v.w);
            reinterpret_cast<ushort4*>(Xb)[i] = o;
        }
    } else {
        int r = (b - XB4) * 256 + threadIdx.x;  // (s*NN + node)
        if (r < NS * NN) {
            const float4* p = reinterpret_cast<const float4*>(noise + (size_t)r * DNOISE);
            float4* oe = reinterpret_cast<float4*>(out_eps + (size_t)r * DNOISE);
            unsigned int lo = 0, hi = 0;
            for (int q = 0; q < 8; ++q) {
                float4 v = p[q];
                oe[q] = v;
                int base = q * 4;
                lo |= (v.x != 0.f ? 1u : 0u) << base;
                lo |= (v.y != 0.f ? 1u : 0u) << (base + 1);
                lo |= (v.z != 0.f ? 1u : 0u) << (base + 2);
                lo |= (v.w != 0.f ? 1u : 0u) << (base + 3);
            }
            for (int q = 8; q < 16; ++q) {
                float4 v = p[q];
                oe[q] = v;
                int base = q * 4 - 32;
                hi |= (v.x != 0.f ? 1u : 0u) << base;
                hi |= (v.y != 0.f ? 1u : 0u) << (base + 1);
                hi |= (v.z != 0.f ? 1u : 0u) << (base + 2);
                hi |= (v.w != 0.f ? 1u : 0u) << (base + 3);
            }
            uint2 o; o.x = lo; o.y = hi;
            Nbit[r] = o;
        }
    }
}

// ---------------- W transposes, both layers in one launch ----------------

__global__ void transpose_both(const float* __restrict__ W0, const float* __restrict__ W1,
                               __hip_bfloat16* __restrict__ Wt0, __hip_bfloat16* __restrict__ Wt1) {
    int b = blockIdx.x;
    if (b < DOUT) {
        for (int k = threadIdx.x; k < DH0; k += blockDim.x)
            Wt0[(size_t)b * DH0 + k] = __float2bfloat16(W0[(size_t)k * DOUT + b]);
    } else {
        int n = b - DOUT;
        for (int k = threadIdx.x; k < DOUT; k += blockDim.x)
            Wt1[(size_t)n * DOUT + k] = __float2bfloat16(W1[(size_t)k * DOUT + n]);
    }
}

// ---------------- Layer 0 aggregation ----------------
// 2 nodes/block (slot = tid>>7), 128 threads/node:
//   cc in [0,64): X uints, gathered from Xb, written to BOTH samples (dedup).
//   cc in [64,128): noise via bitpacked table (L2-resident, 800 KB).

__global__ __launch_bounds__(256) void agg0_kernel(
    const unsigned int* __restrict__ Xb,   // [NN][64] packed bf16 pairs
    const uint2* __restrict__ Nbit,        // [NS*NN] 64 noise bits
    const int* __restrict__ row_ptr, const int* __restrict__ col_idx,
    const float* __restrict__ eps0p,
    unsigned int* __restrict__ z0) {       // [NS*NN][96]
    const int d = blockIdx.x * 2 + (threadIdx.x >> 7);
    const int cc = threadIdx.x & 127;
    const float c = 1.f + eps0p[0];
    const int beg = row_ptr[d], end = row_ptr[d + 1];
    if (cc < 64) {
        const unsigned int* src = Xb + cc;
        unsigned int u = src[(size_t)d * 64];
        float aL = c * bflo(u), aH = c * bfhi(u);
        int e = beg;
        for (; e + 3 < end; e += 4) {
            int i0 = col_idx[e], i1 = col_idx[e + 1], i2 = col_idx[e + 2], i3 = col_idx[e + 3];
            unsigned int u0 = src[(size_t)i0 * 64], u1 = src[(size_t)i1 * 64];
            unsigned int u2 = src[(size_t)i2 * 64], u3 = src[(size_t)i3 * 64];
            aL += (bflo(u0) + bflo(u1)) + (bflo(u2) + bflo(u3));
            aH += (bfhi(u0) + bfhi(u1)) + (bfhi(u2) + bfhi(u3));
        }
        for (; e < end; ++e) {
            unsigned int ue = src[(size_t)col_idx[e] * 64];
            aL += bflo(ue); aH += bfhi(ue);
        }
        unsigned int r = pack2(aL, aH);
        z0[(size_t)d * 96 + cc] = r;             // sample 0
        z0[(size_t)(NN + d) * 96 + cc] = r;      // sample 1 (X part sample-independent)
    } else {
        int j = cc - 64;
        int s = j >> 5, col = j & 31;            // dims 2*col, 2*col+1
        const uint2* src = Nbit + (size_t)s * NN;
        const int word = col >> 4;               // 0 -> .x, 1 -> .y
        const int sh = (2 * col) & 31;
        uint2 uS = src[d];
        unsigned int wS = word ? uS.y : uS.x;
        int c0 = 0, c1 = 0;
        int e = beg;
        for (; e + 3 < end; e += 4) {
            uint2 u0 = src[col_idx[e]], u1 = src[col_idx[e + 1]];
            uint2 u2 = src[col_idx[e + 2]], u3 = src[col_idx[e + 3]];
            unsigned int w0 = word ? u0.y : u0.x, w1 = word ? u1.y : u1.x;
            unsigned int w2 = word ? u2.y : u2.x, w3 = word ? u3.y : u3.x;
            c0 += (int)((w0 >> sh) & 1) + (int)((w1 >> sh) & 1) + (int)((w2 >> sh) & 1) + (int)((w3 >> sh) & 1);
            c1 += (int)((w0 >> (sh + 1)) & 1) + (int)((w1 >> (sh + 1)) & 1) +
                  (int)((w2 >> (sh + 1)) & 1) + (int)((w3 >> (sh + 1)) & 1);
        }
        for (; e < end; ++e) {
            uint2 ue = src[col_idx[e]];
            unsigned int we = word ? ue.y : ue.x;
            c0 += (int)((we >> sh) & 1);
            c1 += (int)((we >> (sh + 1)) & 1);
        }
        float aL = c * (float)((wS >> sh) & 1) + (float)c0;
        float aH = c * (float)((wS >> (sh + 1)) & 1) + (float)c1;
        z0[(size_t)(s * NN + d) * 96 + 64 + col] = pack2(aL, aH);
    }
}

// ---------------- Layer 1 aggregation (round-0 proven version) ----------------
// 2 nodes/block, per node 2 sample-waves of 64 lanes; uint2 gathers (512B/instr),
// x8 unroll. Measured 116 us @ 76% occupancy.

__global__ __launch_bounds__(256) void agg1_kernel(
    const uint2* __restrict__ h,           // [NS*NN][64] (uint2 = 4 bf16)
    const int* __restrict__ row_ptr, const int* __restrict__ col_idx,
    const float* __restrict__ eps1p,
    uint2* __restrict__ z1) {              // [NS*NN][64]
    const int d = blockIdx.x * 2 + (threadIdx.x >> 7);
    const int s = (threadIdx.x >> 6) & 1;
    const int cc = threadIdx.x & 63;
    const float c = 1.f + eps1p[0];
    const int beg = row_ptr[d], end = row_ptr[d + 1];
    const uint2* src = h + (size_t)s * NN * 64 + cc;
    uint2 u = src[(size_t)d * 64];
    float aL0 = c * bflo(u.x), aH0 = c * bfhi(u.x);
    float aL1 = c * bflo(u.y), aH1 = c * bfhi(u.y);
    int e = beg;
    for (; e + 7 < end; e += 8) {
        uint2 g[8];
#pragma unroll
        for (int q = 0; q < 8; ++q) g[q] = src[(size_t)col_idx[e + q] * 64];
#pragma unroll
        for (int q = 0; q < 8; ++q) {
            aL0 += bflo(g[q].x); aH0 += bfhi(g[q].x);
            aL1 += bflo(g[q].y); aH1 += bfhi(g[q].y);
        }
    }
    for (; e + 3 < end; e += 4) {
        uint2 u0 = src[(size_t)col_idx[e] * 64], u1 = src[(size_t)col_idx[e + 1] * 64];
        uint2 u2 = src[(size_t)col_idx[e + 2] * 64], u3 = src[(size_t)col_idx[e + 3] * 64];
        aL0 += (bflo(u0.x) + bflo(u1.x)) + (bflo(u2.x) + bflo(u3.x));
        aH0 += (bfhi(u0.x) + bfhi(u1.x)) + (bfhi(u2.x) + bfhi(u3.x));
        aL1 += (bflo(u0.y) + bflo(u1.y)) + (bflo(u2.y) + bflo(u3.y));
        aH1 += (bfhi(u0.y) + bfhi(u1.y)) + (bfhi(u2.y) + bfhi(u3.y));
    }
    for (; e < end; ++e) {
        uint2 ue = src[(size_t)col_idx[e] * 64];
        aL0 += bflo(ue.x); aH0 += bfhi(ue.x);
        aL1 += bflo(ue.y); aH1 += bfhi(ue.y);
    }
    uint2 r; r.x = pack2(aL0, aH0); r.y = pack2(aL1, aH1);
    z1[(size_t)(s * NN + d) * 64 + cc] = r;
}

// ---------------- GEMM: C = relu(A @ W + b), N fixed at 256 ----------------
// LDS-staged B. Block = 256 threads = 4 waves; block tile = 256 rows x 64 cols.
// Each wave: 64 rows x 64 cols = 4x4 fragment grid of 16x16x32 MFMA
// (acc = 64 VGPRs; 2x the B-reuse of the 32-row layout -> LDS-BW ceiling ~60%).
// B chunk [64 cols][64 k] = 8 KB LDS, XOR-swizzled 16B slots: write slot
// j^(n&7), read slot (ks*4+quad)^(n&7) -> uniform 8 lanes per 16B slot =
// conflict-free b128. Next chunk prefetched to regs during compute.
// XCD swizzle: 4 col-group siblings of a row-group map to the SAME XCD,
// adjacent in dispatch -> A rows re-read by siblings are L2-hits.
// Per-lane MFMA operands identical to previous version (same numerics).

__device__ inline void store_out(float* C, size_t idx, float v) { C[idx] = v; }
__device__ inline void store_out(__hip_bfloat16* C, size_t idx, float v) { C[idx] = __float2bfloat16(v); }

template <int K, typename OUT_T>
__global__ __launch_bounds__(256) void gemm_bias_relu(
    const __hip_bfloat16* __restrict__ A, const __hip_bfloat16* __restrict__ Wt,
    const float* __restrict__ bias, OUT_T* __restrict__ C, int M) {
    __shared__ uint4 ldsbuf[512];              // 8 KB: B chunk [64 n][64 k] bf16, swizzled
    char* lds = (char*)ldsbuf;

    // physical -> logical block swizzle (bijective; 1568 blocks = 392 rg x 4 cg)
    const int p = blockIdx.x;
    const int mm = p >> 3, rr8 = p & 7;
    const int cg = mm & 3, qq = mm >> 2;
    const int rg = qq * 8 + rr8;               // row-group of 256 rows
    const int blockRow = rg * 256;
    if (blockRow >= M) return;                  // uniform across block
    const int colBase = cg * 64;

    const int tid = threadIdx.x;
    const int lane = tid & 63;
    const int wave = tid >> 6;
    const int lo = lane & 15, quad = lane >> 4;
    const int rowBase = blockRow + wave * 64;

    // staging: thread covers 16B slots (n0, j0) and (n0+32, j0)
    const int n0 = tid >> 3, j0 = tid & 7;
    const int n1 = n0 + 32;
    const __hip_bfloat16* wg0 = Wt + (size_t)(colBase + n0) * K + j0 * 8;
    const __hip_bfloat16* wg1 = Wt + (size_t)(colBase + n1) * K + j0 * 8;
    const int lw0 = n0 * 128 + ((j0 ^ (n0 & 7)) << 4);
    const int lw1 = n1 * 128 + ((j0 ^ (n1 & 7)) << 4);

    floatx4 acc[4][4];
#pragma unroll
    for (int i = 0; i < 4; ++i)
#pragma unroll
        for (int j = 0; j < 4; ++j) acc[i][j] = (floatx4){0.f, 0.f, 0.f, 0.f};

    // clamped A row byte offsets (tail block: clamp loads, guard stores)
    unsigned int aoff[4];
#pragma unroll
    for (int rt = 0; rt < 4; ++rt) {
        int rowi = rowBase + rt * 16 + lo;
        if (rowi >= M) rowi = M - 1;
        aoff[rt] = (unsigned int)rowi * (unsigned int)(K * 2);
    }
    const char* Ab = (const char*)A + quad * 16;

    const int NC = K >> 6;                     // 64-wide k-chunks (3 or 4)

    // prologue: stage chunk 0
    {
        uint4 s0 = *(const uint4*)wg0;
        uint4 s1 = *(const uint4*)wg1;
        *(uint4*)(lds + lw0) = s0;
        *(uint4*)(lds + lw1) = s1;
    }
    __syncthreads();

    for (int c = 0; c < NC; ++c) {
        uint4 q0 = {0, 0, 0, 0}, q1 = {0, 0, 0, 0};
        if (c + 1 < NC) {                       // prefetch next chunk to regs
            q0 = *(const uint4*)(wg0 + (c + 1) * 64);
            q1 = *(const uint4*)(wg1 + (c + 1) * 64);
        }
#pragma unroll
        for (int ks = 0; ks < 2; ++ks) {
            bf16x8 a[4], b[4];
            const int kbyte = c * 128 + ks * 64;
#pragma unroll
            for (int rt = 0; rt < 4; ++rt)
                a[rt] = *(const bf16x8*)(Ab + aoff[rt] + kbyte);
#pragma unroll
            for (int ct = 0; ct < 4; ++ct) {
                int nr = ct * 16 + lo;
                b[ct] = *(const bf16x8*)(lds + nr * 128 + ((((ks << 2) + quad) ^ (nr & 7)) << 4));
            }
#pragma unroll
            for (int rt = 0; rt < 4; ++rt)
#pragma unroll
                for (int ct = 0; ct < 4; ++ct)
                    acc[rt][ct] = __builtin_amdgcn_mfma_f32_16x16x32_bf16(a[rt], b[ct], acc[rt][ct], 0, 0, 0);
        }
        __syncthreads();
        if (c + 1 < NC) {
            *(uint4*)(lds + lw0) = q0;
            *(uint4*)(lds + lw1) = q1;
            __syncthreads();
        }
    }

#pragma unroll
    for (int ct = 0; ct < 4; ++ct) {
        const int col = colBase + ct * 16 + lo;
        const float bv = bias[col];
#pragma unroll
        for (int rt = 0; rt < 4; ++rt) {
#pragma unroll
            for (int r = 0; r < 4; ++r) {
                int row = rowBase + rt * 16 + quad * 4 + r;
                if (row < M) {
                    float v = acc[rt][ct][r] + bv;
                    store_out(C, (size_t)row * DOUT + col, v > 0.f ? v : 0.f);
                }
            }
        }
    }
}

#define GEMM_GRID 1568   // 392 row-groups (ceil(100000/256) padded to %8) x 4 col-groups

extern "C" void kernel_launch(void* const* d_in, const int* in_sizes, int n_in,
                              void* d_out, int out_size, void* d_ws, size_t ws_size,
                              hipStream_t stream) {
    const float* X = (const float*)d_in[0];
    const float* noise = (const float*)d_in[1];
    const int* esrc = (const int*)d_in[2];
    const int* edst = (const int*)d_in[3];
    const float* W0 = (const float*)d_in[4];
    const float* b0 = (const float*)d_in[5];
    const float* W1 = (const float*)d_in[6];
    const float* b1 = (const float*)d_in[7];
    const float* eps0 = (const float*)d_in[8];
    const float* eps1 = (const float*)d_in[9];
    float* out = (float*)d_out;

    const int M = NS * NN;  // 100000

    // Workspace carve (~56 MB, proven footprint).
    char* w = (char*)d_ws;
    auto carve = [&](size_t bytes) { char* p = w; w += (bytes + 511) & ~(size_t)511; return p; };
    int* cursor = (int*)carve((size_t)NN * 4);
    int* row_ptr = (int*)carve((size_t)(NN + 1) * 4);
    int* col_idx = (int*)carve((size_t)NE * 4);
    int* bsum = (int*)carve((size_t)NB * 4);
    uint2* Nbit = (uint2*)carve((size_t)M * 8);                    // 800 KB, L2-resident
    __hip_bfloat16* Wt0 = (__hip_bfloat16*)carve((size_t)DH0 * DOUT * 2);
    __hip_bfloat16* Wt1 = (__hip_bfloat16*)carve((size_t)DOUT * DOUT * 2);
    unsigned int* z = (unsigned int*)carve((size_t)M * DOUT * 2);  // z0 (96 uints/row) then z1 (64 uint2/row)

    // h1 (bf16, [s][node][256], 51.2 MB) staged at the start of the fp32 out
    // region (102.4 MB); dead before gemm1 overwrites it.
    __hip_bfloat16* h1 = (__hip_bfloat16*)d_out;
    // bf16 X copy (12.8 MB) lives in the TAIL of the z region: z0 occupies
    // [M][96] uints = 38.4 MB of the 51.2 MB carve; the remaining 12.8 MB
    // exactly fits Xb. Xb is dead after agg0; agg1's z1 write overwrites it.
    // This frees the epsilon output region so prep writes epsilon directly.
    unsigned short* Xb = (unsigned short*)(z + (size_t)M * 96);

    hipMemsetAsync(cursor, 0, (size_t)NN * 4, stream);
    count_kernel<<<(NE + 255) / 256, 256, 0, stream>>>(edst, cursor);
    scanA_kernel<<<NB, 1024, 0, stream>>>(cursor, bsum);
    scanB_kernel<<<1, 64, 0, stream>>>(bsum);
    scanC_kernel<<<NB, 1024, 0, stream>>>(cursor, bsum, row_ptr);
    fill_kernel<<<(NE + 255) / 256, 256, 0, stream>>>(esrc, edst, cursor, col_idx);
    prep_kernel<<<XB4 + NR_BLOCKS, 256, 0, stream>>>(X, Xb, noise, Nbit,
                                                     out + (size_t)M * DOUT);
    transpose_both<<<2 * DOUT, 256, 0, stream>>>(W0, W1, Wt0, Wt1);

    agg0_kernel<<<NN / 2, 256, 0, stream>>>(
        (const unsigned int*)Xb, Nbit, row_ptr, col_idx, eps0, z);
    gemm_bias_relu<DH0, __hip_bfloat16><<<GEMM_GRID, 256, 0, stream>>>(
        (const __hip_bfloat16*)z, Wt0, b0, h1, M);
    agg1_kernel<<<NN / 2, 256, 0, stream>>>(
        (const uint2*)h1, row_ptr, col_idx, eps1, (uint2*)z);
    gemm_bias_relu<DOUT, float><<<GEMM_GRID, 256, 0, stream>>>(
        (const __hip_bfloat16*)z, Wt1, b1, out, M);
}